// Round 3
// baseline (865.265 us; speedup 1.0000x reference)
//
#include <hip/hip_runtime.h>

// PTV3 attention: sort -> gather -> QKV GEMM -> blocked MHA -> scatter -> proj GEMM
// All matmuls via v_mfma_f32_16x16x32_bf16 (f32 accum). Threshold is 2% relative
// to ref absmax; bf16 error budget ~3.5e-4 << 2.17e-3.
// NOTE: harness delivers integer inputs as int32 ("integer -> const int*").

typedef unsigned long long u64;
typedef unsigned short ushort_t;
typedef __attribute__((ext_vector_type(4))) short short4v;
typedef __attribute__((ext_vector_type(8))) short short8v;
typedef __attribute__((ext_vector_type(4))) float f32x4;

#define MFMA_BF16 __builtin_amdgcn_mfma_f32_16x16x32_bf16

__device__ __forceinline__ unsigned short f2bf(float f) {
  union { float f; unsigned u; } v; v.f = f;
  return (unsigned short)((v.u + 0x7FFFu + ((v.u >> 16) & 1u)) >> 16);
}

// ---------------- stable sort of (code, idx) per 16384-group ----------------
// key = (code << 14) | idx  (code < 2^30, idx < 2^14) -> stable ascending sort.

__global__ __launch_bounds__(256) void sort_chunk(const int* __restrict__ codes,
                                                  u64* __restrict__ keys) {
  __shared__ u64 sk[2048];
  const int base = blockIdx.x * 2048;
  for (int t = threadIdx.x; t < 2048; t += 256) {
    int e = base + t;
    sk[t] = (((u64)(unsigned)codes[e]) << 14) | (u64)(e & 16383);
  }
  __syncthreads();
  for (int k = 2; k <= 2048; k <<= 1) {
    for (int j = k >> 1; j > 0; j >>= 1) {
      for (int t = threadIdx.x; t < 2048; t += 256) {
        int jx = t ^ j;
        if (jx > t) {
          bool up = (((base + t) & 16383 & k) == 0);
          u64 a = sk[t], b = sk[jx];
          if ((a > b) == up) { sk[t] = b; sk[jx] = a; }
        }
      }
      __syncthreads();
    }
  }
  for (int t = threadIdx.x; t < 2048; t += 256) keys[base + t] = sk[t];
}

__global__ __launch_bounds__(256) void sort_gpass(u64* __restrict__ keys, int k, int j) {
  int t = blockIdx.x * 256 + threadIdx.x;
  int jx = t ^ j;
  if (jx > t) {
    bool up = ((t & 16383 & k) == 0);
    u64 a = keys[t], b = keys[jx];
    if ((a > b) == up) { keys[t] = b; keys[jx] = a; }
  }
}

__global__ __launch_bounds__(256) void sort_finish(u64* __restrict__ keys, int k) {
  __shared__ u64 sk[2048];
  const int base = blockIdx.x * 2048;
  for (int t = threadIdx.x; t < 2048; t += 256) sk[t] = keys[base + t];
  __syncthreads();
  for (int j = 1024; j > 0; j >>= 1) {
    for (int t = threadIdx.x; t < 2048; t += 256) {
      int jx = t ^ j;
      if (jx > t) {
        bool up = (((base + t) & 16383 & k) == 0);
        u64 a = sk[t], b = sk[jx];
        if ((a > b) == up) { sk[t] = b; sk[jx] = a; }
      }
    }
    __syncthreads();
  }
  for (int t = threadIdx.x; t < 2048; t += 256) keys[base + t] = sk[t];
}

__global__ __launch_bounds__(256) void write_perm(const u64* __restrict__ keys,
                                                  int* __restrict__ perm,
                                                  int* __restrict__ iperm) {
  int t = blockIdx.x * 256 + threadIdx.x;
  int g = t >> 14;
  int a = (int)(keys[t] & 16383);
  perm[t] = (g << 14) | a;        // perm[sorted pos] = original row
  iperm[(g << 14) | a] = t;       // iperm[original row] = sorted pos
}

// ---------------- QKV GEMM: C[m][j] = sum_k feats[perm[m]][k] * Wqkv[j][k] + b[j] ----------------
// Scatters to Q[n][h][p][d], K[n][h][p][d], Vt[n][h][d][p]  (bf16)

__global__ __launch_bounds__(256) void qkv_gemm(const float* __restrict__ feats,
    const int* __restrict__ perm, const float* __restrict__ W, const float* __restrict__ bias,
    ushort_t* __restrict__ Q, ushort_t* __restrict__ Ko, ushort_t* __restrict__ Vt)
{
  __shared__ __align__(16) ushort_t la[128][72];
  __shared__ __align__(16) ushort_t lb[128][72];
  const int tid = threadIdx.x;
  const int rowBase = blockIdx.y * 128;
  const int colBase = blockIdx.x * 128;
  const int lane = tid & 63, w = tid >> 6;
  const int wr = w >> 1, wc = w & 1;
  const int li = lane & 15, kb = lane >> 4;
  const int tr = tid >> 4, tc = (tid & 15) << 2;
  f32x4 acc[4][4] = {};
  for (int kt = 0; kt < 8; ++kt) {
#pragma unroll
    for (int p = 0; p < 8; ++p) {
      int row = p * 16 + tr;
      int g = perm[rowBase + row];
      float4 va = *(const float4*)(feats + (size_t)g * 512 + kt * 64 + tc);
      short4v sa = { (short)f2bf(va.x), (short)f2bf(va.y), (short)f2bf(va.z), (short)f2bf(va.w) };
      *(short4v*)(&la[row][tc]) = sa;
      float4 vb = *(const float4*)(W + (size_t)(colBase + row) * 512 + kt * 64 + tc);
      short4v sb = { (short)f2bf(vb.x), (short)f2bf(vb.y), (short)f2bf(vb.z), (short)f2bf(vb.w) };
      *(short4v*)(&lb[row][tc]) = sb;
    }
    __syncthreads();
    short8v af[2][4], bfr[2][4];
#pragma unroll
    for (int kk = 0; kk < 2; ++kk)
#pragma unroll
      for (int t = 0; t < 4; ++t) {
        af[kk][t]  = *(const short8v*)(&la[wr * 64 + t * 16 + li][kk * 32 + kb * 8]);
        bfr[kk][t] = *(const short8v*)(&lb[wc * 64 + t * 16 + li][kk * 32 + kb * 8]);
      }
#pragma unroll
    for (int kk = 0; kk < 2; ++kk)
#pragma unroll
      for (int i = 0; i < 4; ++i)
#pragma unroll
        for (int j = 0; j < 4; ++j)
          acc[i][j] = MFMA_BF16(af[kk][i], bfr[kk][j], acc[i][j], 0, 0, 0);
    __syncthreads();
  }
#pragma unroll
  for (int j = 0; j < 4; ++j) {
    int colb = colBase + wc * 64 + j * 16;
    int col = colb + li;
    float bv = bias[col];
    int c3 = colb >> 9;
    int h = (col >> 6) & 7;
    int d = col & 63;
#pragma unroll
    for (int i = 0; i < 4; ++i) {
      int m0 = rowBase + wr * 64 + i * 16 + kb * 4;
#pragma unroll
      for (int r = 0; r < 4; ++r) {
        int m = m0 + r;
        int n = m >> 9, p = m & 511;
        unsigned short bv16 = f2bf(acc[i][j][r] + bv);
        size_t nh = (size_t)(n * 8 + h);
        if (c3 == 0)      Q [(nh * 512 + p) * 64 + d] = bv16;
        else if (c3 == 1) Ko[(nh * 512 + p) * 64 + d] = bv16;
        else              Vt[(nh * 64 + d) * 512 + p] = bv16;
      }
    }
  }
}

// ---------------- attention: per (n, h), O = softmax(Q K^T / 8) V ----------------
// wave = 16 Q rows; full 512-wide score row in 128 VGPRs; K/V chunks staged in LDS.

__global__ __launch_bounds__(256) void attn_kernel(const ushort_t* __restrict__ Q,
    const ushort_t* __restrict__ K, const ushort_t* __restrict__ Vt, ushort_t* __restrict__ O)
{
  __shared__ __align__(16) ushort_t kbuf[64][72];
  __shared__ __align__(16) ushort_t vbuf[64][72];
  __shared__ __align__(16) ushort_t pbuf[4][16][32];
  const int b = blockIdx.x;
  const int qc = b & 7, h = (b >> 3) & 7, n = b >> 6;
  const int tid = threadIdx.x, w = tid >> 6, lane = tid & 63;
  const int li = lane & 15, kb = lane >> 4;
  const size_t nh = (size_t)(n * 8 + h);
  const ushort_t* Qb = Q + nh * (512 * 64);
  const ushort_t* Kb = K + nh * (512 * 64);
  const ushort_t* Vb = Vt + nh * (64 * 512);
  const int p0 = qc * 64 + w * 16;
  const int sr = tid >> 3, sc = (tid & 7) << 3;

  short8v qf0 = *(const short8v*)(Qb + (size_t)(p0 + li) * 64 + kb * 8);
  short8v qf1 = *(const short8v*)(Qb + (size_t)(p0 + li) * 64 + 32 + kb * 8);

  f32x4 s[32];
  // pass 1: scores
#pragma unroll
  for (int ch = 0; ch < 8; ++ch) {
#pragma unroll
    for (int st = 0; st < 2; ++st) {
      int r = st * 32 + sr;
      *(short8v*)(&kbuf[r][sc]) = *(const short8v*)(Kb + (size_t)(ch * 64 + r) * 64 + sc);
    }
    __syncthreads();
#pragma unroll
    for (int t = 0; t < 4; ++t) {
      short8v kf0 = *(const short8v*)(&kbuf[t * 16 + li][kb * 8]);
      short8v kf1 = *(const short8v*)(&kbuf[t * 16 + li][32 + kb * 8]);
      f32x4 a = {0.f, 0.f, 0.f, 0.f};
      a = MFMA_BF16(qf0, kf0, a, 0, 0, 0);
      a = MFMA_BF16(qf1, kf1, a, 0, 0, 0);
      s[ch * 4 + t] = a;
    }
    __syncthreads();
  }
  // softmax over 512 cols per row; rows of this lane: kb*4 + r
  float mx[4], sm[4], iv[4];
#pragma unroll
  for (int r = 0; r < 4; ++r) mx[r] = -1e30f;
#pragma unroll
  for (int qt = 0; qt < 32; ++qt)
#pragma unroll
    for (int r = 0; r < 4; ++r) mx[r] = fmaxf(mx[r], s[qt][r]);
#pragma unroll
  for (int off = 1; off < 16; off <<= 1)
#pragma unroll
    for (int r = 0; r < 4; ++r) mx[r] = fmaxf(mx[r], __shfl_xor(mx[r], off, 64));
#pragma unroll
  for (int r = 0; r < 4; ++r) sm[r] = 0.f;
  const float cs = 0.125f * 1.44269504088896340736f;  // scale * log2(e)
#pragma unroll
  for (int qt = 0; qt < 32; ++qt)
#pragma unroll
    for (int r = 0; r < 4; ++r) {
      float e = exp2f((s[qt][r] - mx[r]) * cs);
      s[qt][r] = e;
      sm[r] += e;
    }
#pragma unroll
  for (int off = 1; off < 16; off <<= 1)
#pragma unroll
    for (int r = 0; r < 4; ++r) sm[r] += __shfl_xor(sm[r], off, 64);
#pragma unroll
  for (int r = 0; r < 4; ++r) iv[r] = 1.0f / sm[r];

  // pass 2: O += P V (unnormalized P, divide at the end)
  f32x4 o[4] = {};
#pragma unroll
  for (int ch = 0; ch < 8; ++ch) {
#pragma unroll
    for (int st = 0; st < 2; ++st) {
      int r = st * 32 + sr;
      *(short8v*)(&vbuf[r][sc]) = *(const short8v*)(Vb + (size_t)r * 512 + ch * 64 + sc);
    }
    __syncthreads();
#pragma unroll
    for (int u = 0; u < 2; ++u) {
#pragma unroll
      for (int tt = 0; tt < 2; ++tt) {
        int qt = ch * 4 + u * 2 + tt;
#pragma unroll
        for (int r = 0; r < 4; ++r)
          pbuf[w][kb * 4 + r][tt * 16 + li] = f2bf(s[qt][r]);
      }
      __syncthreads();
      short8v pa = *(const short8v*)(&pbuf[w][li][kb * 8]);
#pragma unroll
      for (int dt = 0; dt < 4; ++dt) {
        short8v vf = *(const short8v*)(&vbuf[dt * 16 + li][u * 32 + kb * 8]);
        o[dt] = MFMA_BF16(pa, vf, o[dt], 0, 0, 0);
      }
    }
    __syncthreads();
  }
#pragma unroll
  for (int dt = 0; dt < 4; ++dt)
#pragma unroll
    for (int r = 0; r < 4; ++r) {
      int p = p0 + kb * 4 + r;
      size_t m = (size_t)n * 512 + p;
      O[m * 512 + h * 64 + dt * 16 + li] = f2bf(o[dt][r] * iv[r]);
    }
}

// ---------------- proj GEMM: out[m][c] = sum_k attn[iperm[m]][k] * Wproj[c][k] + b[c] ----------------

__global__ __launch_bounds__(256) void proj_gemm(const ushort_t* __restrict__ A,
    const int* __restrict__ iperm, const float* __restrict__ W, const float* __restrict__ bias,
    float* __restrict__ out)
{
  __shared__ __align__(16) ushort_t la[128][72];
  __shared__ __align__(16) ushort_t lb[128][72];
  const int tid = threadIdx.x;
  const int rowBase = blockIdx.y * 128;
  const int colBase = blockIdx.x * 128;
  const int lane = tid & 63, w = tid >> 6;
  const int wr = w >> 1, wc = w & 1;
  const int li = lane & 15, kb = lane >> 4;
  const int ar = tid >> 3, ac = (tid & 7) << 3;
  const int br = tid >> 4, bc = (tid & 15) << 2;
  f32x4 acc[4][4] = {};
  for (int kt = 0; kt < 8; ++kt) {
#pragma unroll
    for (int p = 0; p < 4; ++p) {
      int row = p * 32 + ar;
      int g = iperm[rowBase + row];
      *(short8v*)(&la[row][ac]) = *(const short8v*)(A + (size_t)g * 512 + kt * 64 + ac);
    }
#pragma unroll
    for (int p = 0; p < 8; ++p) {
      int row = p * 16 + br;
      float4 vb = *(const float4*)(W + (size_t)(colBase + row) * 512 + kt * 64 + bc);
      short4v sb = { (short)f2bf(vb.x), (short)f2bf(vb.y), (short)f2bf(vb.z), (short)f2bf(vb.w) };
      *(short4v*)(&lb[row][bc]) = sb;
    }
    __syncthreads();
    short8v af[2][4], bfr[2][4];
#pragma unroll
    for (int kk = 0; kk < 2; ++kk)
#pragma unroll
      for (int t = 0; t < 4; ++t) {
        af[kk][t]  = *(const short8v*)(&la[wr * 64 + t * 16 + li][kk * 32 + kb * 8]);
        bfr[kk][t] = *(const short8v*)(&lb[wc * 64 + t * 16 + li][kk * 32 + kb * 8]);
      }
#pragma unroll
    for (int kk = 0; kk < 2; ++kk)
#pragma unroll
      for (int i = 0; i < 4; ++i)
#pragma unroll
        for (int j = 0; j < 4; ++j)
          acc[i][j] = MFMA_BF16(af[kk][i], bfr[kk][j], acc[i][j], 0, 0, 0);
    __syncthreads();
  }
#pragma unroll
  for (int i = 0; i < 4; ++i)
#pragma unroll
    for (int j = 0; j < 4; ++j) {
      int col = colBase + wc * 64 + j * 16 + li;
      float bv = bias[col];
#pragma unroll
      for (int r = 0; r < 4; ++r) {
        int m = rowBase + wr * 64 + i * 16 + kb * 4 + r;
        out[(size_t)m * 512 + col] = acc[i][j][r] + bv;
      }
    }
}

// ---------------- launch ----------------

extern "C" void kernel_launch(void* const* d_in, const int* in_sizes, int n_in,
                              void* d_out, int out_size, void* d_ws, size_t ws_size,
                              hipStream_t stream) {
  (void)in_sizes; (void)n_in; (void)out_size; (void)ws_size;
  const float* feats      = (const float*)d_in[0];
  const int* codes        = (const int*)d_in[1];   // int64 in reference, delivered as int32
  const float* Wqkv       = (const float*)d_in[2];
  const float* bqkv       = (const float*)d_in[3];
  const float* Wproj      = (const float*)d_in[4];
  const float* bproj      = (const float*)d_in[5];
  float* out = (float*)d_out;

  // ws layout (needs ~257 MB):
  // [0,256K) perm i32 | [256K,512K) iperm i32 | [512K,1M) sort keys u64
  // [1M,+64M) Q bf16 | +64M K bf16 | +64M Vt bf16 | +64M attn-out bf16
  char* ws = (char*)d_ws;
  int* perm  = (int*)(ws);
  int* iperm = (int*)(ws + 262144);
  u64* keys  = (u64*)(ws + 524288);
  ushort_t* Qb  = (ushort_t*)(ws + (1u << 20));
  ushort_t* Kb  = Qb + 33554432ull;
  ushort_t* Vt  = Kb + 33554432ull;
  ushort_t* att = Vt + 33554432ull;

  sort_chunk<<<32, 256, 0, stream>>>(codes, keys);
  for (int k = 4096; k <= 16384; k <<= 1) {
    for (int j = k >> 1; j >= 2048; j >>= 1)
      sort_gpass<<<256, 256, 0, stream>>>(keys, k, j);
    sort_finish<<<32, 256, 0, stream>>>(keys, k);
  }
  write_perm<<<256, 256, 0, stream>>>(keys, perm, iperm);

  qkv_gemm<<<dim3(12, 512), 256, 0, stream>>>(feats, perm, Wqkv, bqkv, Qb, Kb, Vt);
  attn_kernel<<<8192, 256, 0, stream>>>(Qb, Kb, Vt, att);
  proj_gemm<<<dim3(4, 512), 256, 0, stream>>>(att, iperm, Wproj, bproj, out);
}

// Round 4
// 863.176 us; speedup vs baseline: 1.0024x; 1.0024x over previous
//
#include <hip/hip_runtime.h>

// PTV3 attention: sort -> gather+bf16 prepass -> bf16 QKV GEMM -> blocked MHA
// (scattered write) -> bf16 proj GEMM. GEMMs use m97 structure:
// global_load_lds width-16 staging, linear [128][64] LDS, 2 barriers/K-step,
// XCD-chunked block swizzle.

typedef unsigned long long u64;
typedef unsigned short ushort_t;
typedef __attribute__((ext_vector_type(8))) short short8v;
typedef __attribute__((ext_vector_type(4))) float f32x4;

#define MFMA_BF16 __builtin_amdgcn_mfma_f32_16x16x32_bf16

__device__ __forceinline__ unsigned short f2bf(float f) {
  union { float f; unsigned u; } v; v.f = f;
  return (unsigned short)((v.u + 0x7FFFu + ((v.u >> 16) & 1u)) >> 16);
}

// async global->LDS, 16B per lane; LDS dest = wave-uniform base + lane*16
__device__ __forceinline__ void async16(ushort_t* lds, const ushort_t* g) {
  __builtin_amdgcn_global_load_lds(
      (const __attribute__((address_space(1))) unsigned int*)g,
      (__attribute__((address_space(3))) unsigned int*)lds, 16, 0, 0);
}

// ---------------- stable sort of (code, idx) per 16384-group ----------------
// key = (code << 14) | idx  (code < 2^30, idx < 2^14) -> stable ascending sort.

__global__ __launch_bounds__(256) void sort_chunk(const int* __restrict__ codes,
                                                  u64* __restrict__ keys) {
  __shared__ u64 sk[2048];
  const int base = blockIdx.x * 2048;
  for (int t = threadIdx.x; t < 2048; t += 256) {
    int e = base + t;
    sk[t] = (((u64)(unsigned)codes[e]) << 14) | (u64)(e & 16383);
  }
  __syncthreads();
  for (int k = 2; k <= 2048; k <<= 1) {
    for (int j = k >> 1; j > 0; j >>= 1) {
      for (int t = threadIdx.x; t < 2048; t += 256) {
        int jx = t ^ j;
        if (jx > t) {
          bool up = (((base + t) & 16383 & k) == 0);
          u64 a = sk[t], b = sk[jx];
          if ((a > b) == up) { sk[t] = b; sk[jx] = a; }
        }
      }
      __syncthreads();
    }
  }
  for (int t = threadIdx.x; t < 2048; t += 256) keys[base + t] = sk[t];
}

__global__ __launch_bounds__(256) void sort_gpass(u64* __restrict__ keys, int k, int j) {
  int t = blockIdx.x * 256 + threadIdx.x;
  int jx = t ^ j;
  if (jx > t) {
    bool up = ((t & 16383 & k) == 0);
    u64 a = keys[t], b = keys[jx];
    if ((a > b) == up) { keys[t] = b; keys[jx] = a; }
  }
}

__global__ __launch_bounds__(256) void sort_finish(u64* __restrict__ keys, int k) {
  __shared__ u64 sk[2048];
  const int base = blockIdx.x * 2048;
  for (int t = threadIdx.x; t < 2048; t += 256) sk[t] = keys[base + t];
  __syncthreads();
  for (int j = 1024; j > 0; j >>= 1) {
    for (int t = threadIdx.x; t < 2048; t += 256) {
      int jx = t ^ j;
      if (jx > t) {
        bool up = (((base + t) & 16383 & k) == 0);
        u64 a = sk[t], b = sk[jx];
        if ((a > b) == up) { sk[t] = b; sk[jx] = a; }
      }
    }
    __syncthreads();
  }
  for (int t = threadIdx.x; t < 2048; t += 256) keys[base + t] = sk[t];
}

__global__ __launch_bounds__(256) void write_perm(const u64* __restrict__ keys,
                                                  int* __restrict__ perm) {
  int t = blockIdx.x * 256 + threadIdx.x;
  int g = t >> 14;
  int a = (int)(keys[t] & 16383);
  perm[t] = (g << 14) | a;        // perm[sorted pos] = original row
}

// ---------------- prepass: Abf[m][k] = bf16(feats[perm[m]][k]) ----------------
// 16 elems/thread: 2,097,152 threads.

__global__ __launch_bounds__(256) void gather_bf16(const float* __restrict__ feats,
    const int* __restrict__ perm, ushort_t* __restrict__ A) {
  int t = blockIdx.x * 256 + threadIdx.x;
  int m = t >> 5;
  int off = (t & 31) << 4;
  const float* src = feats + (size_t)perm[m] * 512 + off;
  float4 a = ((const float4*)src)[0];
  float4 b = ((const float4*)src)[1];
  float4 c = ((const float4*)src)[2];
  float4 d = ((const float4*)src)[3];
  short8v lo = { (short)f2bf(a.x), (short)f2bf(a.y), (short)f2bf(a.z), (short)f2bf(a.w),
                 (short)f2bf(b.x), (short)f2bf(b.y), (short)f2bf(b.z), (short)f2bf(b.w) };
  short8v hi = { (short)f2bf(c.x), (short)f2bf(c.y), (short)f2bf(c.z), (short)f2bf(c.w),
                 (short)f2bf(d.x), (short)f2bf(d.y), (short)f2bf(d.z), (short)f2bf(d.w) };
  ushort_t* dst = A + (size_t)m * 512 + off;
  *(short8v*)(dst) = lo;
  *(short8v*)(dst + 8) = hi;
}

__global__ __launch_bounds__(256) void convert_bf16(const float* __restrict__ src,
                                                    ushort_t* __restrict__ dst) {
  int t = blockIdx.x * 256 + threadIdx.x;
  const float* s = src + (size_t)t * 8;
  float4 a = ((const float4*)s)[0];
  float4 b = ((const float4*)s)[1];
  short8v v = { (short)f2bf(a.x), (short)f2bf(a.y), (short)f2bf(a.z), (short)f2bf(a.w),
                (short)f2bf(b.x), (short)f2bf(b.y), (short)f2bf(b.z), (short)f2bf(b.w) };
  *(short8v*)(dst + (size_t)t * 8) = v;
}

// ---------------- QKV GEMM (bf16): C[m][j] = sum_k A[m][k]*W[j][k] + b[j] ----------------
// A: 65536x512 bf16 (pre-gathered), W: 1536x512 bf16.
// Scatters to Q[n][h][p][d], K[n][h][p][d], Vt[n][h][d][p]  (bf16)

__global__ __launch_bounds__(256) void qkv_gemm(const ushort_t* __restrict__ A,
    const ushort_t* __restrict__ W, const float* __restrict__ bias,
    ushort_t* __restrict__ Q, ushort_t* __restrict__ Ko, ushort_t* __restrict__ Vt)
{
  __shared__ __align__(16) ushort_t la[128 * 64];
  __shared__ __align__(16) ushort_t lb[128 * 64];
  const int bid = blockIdx.x;                 // 6144 = 12 x 512, XCD-chunked
  const int swz = (bid & 7) * 768 + (bid >> 3);
  const int bx = swz % 12, by = swz / 12;
  const int rowBase = by * 128, colBase = bx * 128;
  const int tid = threadIdx.x, lane = tid & 63, w = tid >> 6;
  const int wr = w >> 1, wc = w & 1;
  const int li = lane & 15, kb = lane >> 4;
  const int lr = lane >> 3, lc = (lane & 7) << 3;   // gload: row-in-chunk, col
  f32x4 acc[4][4] = {};
  for (int kt = 0; kt < 8; ++kt) {
#pragma unroll
    for (int i = 0; i < 4; ++i) {
      int c = w * 4 + i;                       // chunk: rows 8c..8c+7
      async16(la + c * 512, A + (size_t)(rowBase + c * 8 + lr) * 512 + kt * 64 + lc);
      async16(lb + c * 512, W + (size_t)(colBase + c * 8 + lr) * 512 + kt * 64 + lc);
    }
    __syncthreads();
    short8v af[2][4], bfr[2][4];
#pragma unroll
    for (int kk = 0; kk < 2; ++kk)
#pragma unroll
      for (int t = 0; t < 4; ++t) {
        af[kk][t]  = *(const short8v*)(la + (wr * 64 + t * 16 + li) * 64 + kk * 32 + kb * 8);
        bfr[kk][t] = *(const short8v*)(lb + (wc * 64 + t * 16 + li) * 64 + kk * 32 + kb * 8);
      }
#pragma unroll
    for (int kk = 0; kk < 2; ++kk)
#pragma unroll
      for (int i = 0; i < 4; ++i)
#pragma unroll
        for (int j = 0; j < 4; ++j)
          acc[i][j] = MFMA_BF16(af[kk][i], bfr[kk][j], acc[i][j], 0, 0, 0);
    __syncthreads();
  }
#pragma unroll
  for (int j = 0; j < 4; ++j) {
    int colb = colBase + wc * 64 + j * 16;
    int col = colb + li;
    float bv = bias[col];
    int c3 = colb >> 9;
    int h = (col >> 6) & 7;
    int d = col & 63;
#pragma unroll
    for (int i = 0; i < 4; ++i) {
      int m0 = rowBase + wr * 64 + i * 16 + kb * 4;
#pragma unroll
      for (int r = 0; r < 4; ++r) {
        int m = m0 + r;
        int n = m >> 9, p = m & 511;
        unsigned short bv16 = f2bf(acc[i][j][r] + bv);
        size_t nh = (size_t)(n * 8 + h);
        if (c3 == 0)      Q [(nh * 512 + p) * 64 + d] = bv16;
        else if (c3 == 1) Ko[(nh * 512 + p) * 64 + d] = bv16;
        else              Vt[(nh * 64 + d) * 512 + p] = bv16;
      }
    }
  }
}

// ---------------- attention: per (n, h), O = softmax(Q K^T / 8) V ----------------
// wave = 16 Q rows; full 512-wide score row in 128 VGPRs; K/V chunks staged in LDS.
// Output written SCATTERED to original row order via perm.

__global__ __launch_bounds__(256) void attn_kernel(const ushort_t* __restrict__ Q,
    const ushort_t* __restrict__ K, const ushort_t* __restrict__ Vt,
    const int* __restrict__ perm, ushort_t* __restrict__ O)
{
  __shared__ __align__(16) ushort_t kbuf[64][72];
  __shared__ __align__(16) ushort_t vbuf[64][72];
  __shared__ __align__(16) ushort_t pbuf[4][16][32];
  const int b = blockIdx.x;
  const int qc = b & 7, h = (b >> 3) & 7, n = b >> 6;
  const int tid = threadIdx.x, w = tid >> 6, lane = tid & 63;
  const int li = lane & 15, kb = lane >> 4;
  const size_t nh = (size_t)(n * 8 + h);
  const ushort_t* Qb = Q + nh * (512 * 64);
  const ushort_t* Kb = K + nh * (512 * 64);
  const ushort_t* Vb = Vt + nh * (64 * 512);
  const int p0 = qc * 64 + w * 16;
  const int sr = tid >> 3, sc = (tid & 7) << 3;

  short8v qf0 = *(const short8v*)(Qb + (size_t)(p0 + li) * 64 + kb * 8);
  short8v qf1 = *(const short8v*)(Qb + (size_t)(p0 + li) * 64 + 32 + kb * 8);

  f32x4 s[32];
  // pass 1: scores
#pragma unroll
  for (int ch = 0; ch < 8; ++ch) {
#pragma unroll
    for (int st = 0; st < 2; ++st) {
      int r = st * 32 + sr;
      *(short8v*)(&kbuf[r][sc]) = *(const short8v*)(Kb + (size_t)(ch * 64 + r) * 64 + sc);
    }
    __syncthreads();
#pragma unroll
    for (int t = 0; t < 4; ++t) {
      short8v kf0 = *(const short8v*)(&kbuf[t * 16 + li][kb * 8]);
      short8v kf1 = *(const short8v*)(&kbuf[t * 16 + li][32 + kb * 8]);
      f32x4 a = {0.f, 0.f, 0.f, 0.f};
      a = MFMA_BF16(qf0, kf0, a, 0, 0, 0);
      a = MFMA_BF16(qf1, kf1, a, 0, 0, 0);
      s[ch * 4 + t] = a;
    }
    __syncthreads();
  }
  // softmax over 512 cols per row; rows of this lane: kb*4 + r
  float mx[4], sm[4], iv[4];
#pragma unroll
  for (int r = 0; r < 4; ++r) mx[r] = -1e30f;
#pragma unroll
  for (int qt = 0; qt < 32; ++qt)
#pragma unroll
    for (int r = 0; r < 4; ++r) mx[r] = fmaxf(mx[r], s[qt][r]);
#pragma unroll
  for (int off = 1; off < 16; off <<= 1)
#pragma unroll
    for (int r = 0; r < 4; ++r) mx[r] = fmaxf(mx[r], __shfl_xor(mx[r], off, 64));
#pragma unroll
  for (int r = 0; r < 4; ++r) sm[r] = 0.f;
  const float cs = 0.125f * 1.44269504088896340736f;  // scale * log2(e)
#pragma unroll
  for (int qt = 0; qt < 32; ++qt)
#pragma unroll
    for (int r = 0; r < 4; ++r) {
      float e = exp2f((s[qt][r] - mx[r]) * cs);
      s[qt][r] = e;
      sm[r] += e;
    }
#pragma unroll
  for (int off = 1; off < 16; off <<= 1)
#pragma unroll
    for (int r = 0; r < 4; ++r) sm[r] += __shfl_xor(sm[r], off, 64);
#pragma unroll
  for (int r = 0; r < 4; ++r) iv[r] = 1.0f / sm[r];

  // pass 2: O += P V (unnormalized P, divide at the end)
  f32x4 o[4] = {};
#pragma unroll
  for (int ch = 0; ch < 8; ++ch) {
#pragma unroll
    for (int st = 0; st < 2; ++st) {
      int r = st * 32 + sr;
      *(short8v*)(&vbuf[r][sc]) = *(const short8v*)(Vb + (size_t)r * 512 + ch * 64 + sc);
    }
    __syncthreads();
#pragma unroll
    for (int u = 0; u < 2; ++u) {
#pragma unroll
      for (int tt = 0; tt < 2; ++tt) {
        int qt = ch * 4 + u * 2 + tt;
#pragma unroll
        for (int r = 0; r < 4; ++r)
          pbuf[w][kb * 4 + r][tt * 16 + li] = f2bf(s[qt][r]);
      }
      __syncthreads();
      short8v pa = *(const short8v*)(&pbuf[w][li][kb * 8]);
#pragma unroll
      for (int dt = 0; dt < 4; ++dt) {
        short8v vf = *(const short8v*)(&vbuf[dt * 16 + li][u * 32 + kb * 8]);
        o[dt] = MFMA_BF16(pa, vf, o[dt], 0, 0, 0);
      }
    }
    __syncthreads();
  }
  int op[4];
#pragma unroll
  for (int r = 0; r < 4; ++r)
    op[r] = perm[n * 512 + p0 + kb * 4 + r];   // original row for sorted row
#pragma unroll
  for (int dt = 0; dt < 4; ++dt)
#pragma unroll
    for (int r = 0; r < 4; ++r)
      O[(size_t)op[r] * 512 + h * 64 + dt * 16 + li] = f2bf(o[dt][r] * iv[r]);
}

// ---------------- proj GEMM (bf16): out[m][c] = sum_k att[m][k]*Wp[c][k] + b[c] ----------------
// att already in original row order -> fully contiguous A.

__global__ __launch_bounds__(256) void proj_gemm(const ushort_t* __restrict__ A,
    const ushort_t* __restrict__ W, const float* __restrict__ bias,
    float* __restrict__ out)
{
  __shared__ __align__(16) ushort_t la[128 * 64];
  __shared__ __align__(16) ushort_t lb[128 * 64];
  const int bid = blockIdx.x;                 // 2048 = 4 x 512, XCD-chunked
  const int swz = (bid & 7) * 256 + (bid >> 3);
  const int bx = swz & 3, by = swz >> 2;
  const int rowBase = by * 128, colBase = bx * 128;
  const int tid = threadIdx.x, lane = tid & 63, w = tid >> 6;
  const int wr = w >> 1, wc = w & 1;
  const int li = lane & 15, kb = lane >> 4;
  const int lr = lane >> 3, lc = (lane & 7) << 3;
  f32x4 acc[4][4] = {};
  for (int kt = 0; kt < 8; ++kt) {
#pragma unroll
    for (int i = 0; i < 4; ++i) {
      int c = w * 4 + i;
      async16(la + c * 512, A + (size_t)(rowBase + c * 8 + lr) * 512 + kt * 64 + lc);
      async16(lb + c * 512, W + (size_t)(colBase + c * 8 + lr) * 512 + kt * 64 + lc);
    }
    __syncthreads();
    short8v af[2][4], bfr[2][4];
#pragma unroll
    for (int kk = 0; kk < 2; ++kk)
#pragma unroll
      for (int t = 0; t < 4; ++t) {
        af[kk][t]  = *(const short8v*)(la + (wr * 64 + t * 16 + li) * 64 + kk * 32 + kb * 8);
        bfr[kk][t] = *(const short8v*)(lb + (wc * 64 + t * 16 + li) * 64 + kk * 32 + kb * 8);
      }
#pragma unroll
    for (int kk = 0; kk < 2; ++kk)
#pragma unroll
      for (int i = 0; i < 4; ++i)
#pragma unroll
        for (int j = 0; j < 4; ++j)
          acc[i][j] = MFMA_BF16(af[kk][i], bfr[kk][j], acc[i][j], 0, 0, 0);
    __syncthreads();
  }
#pragma unroll
  for (int i = 0; i < 4; ++i)
#pragma unroll
    for (int j = 0; j < 4; ++j) {
      int col = colBase + wc * 64 + j * 16 + li;
      float bv = bias[col];
#pragma unroll
      for (int r = 0; r < 4; ++r) {
        int m = rowBase + wr * 64 + i * 16 + kb * 4 + r;
        out[(size_t)m * 512 + col] = acc[i][j][r] + bv;
      }
    }
}

// ---------------- launch ----------------

extern "C" void kernel_launch(void* const* d_in, const int* in_sizes, int n_in,
                              void* d_out, int out_size, void* d_ws, size_t ws_size,
                              hipStream_t stream) {
  (void)in_sizes; (void)n_in; (void)out_size; (void)ws_size;
  const float* feats      = (const float*)d_in[0];
  const int* codes        = (const int*)d_in[1];   // int64 in reference, delivered as int32
  const float* Wqkv       = (const float*)d_in[2];
  const float* bqkv       = (const float*)d_in[3];
  const float* Wproj      = (const float*)d_in[4];
  const float* bproj      = (const float*)d_in[5];
  float* out = (float*)d_out;

  // ws layout (~259 MB):
  // [0,256K) perm | [256K,384K) keys | [1M,+64M) Abf (reused as att) |
  // +1.5M Wqkvbf | +0.5M Wprojbf | 3x64M Q,K,Vt
  char* ws = (char*)d_ws;
  int* perm = (int*)(ws);
  u64* keys = (u64*)(ws + 262144);
  ushort_t* Abf     = (ushort_t*)(ws + 1048576);          // 64 MB
  ushort_t* att     = Abf;                                 // reuse (Abf dead after qkv)
  ushort_t* Wqkvbf  = (ushort_t*)(ws + 1048576 + 67108864);            // 1.5 MB
  ushort_t* Wprojbf = (ushort_t*)(ws + 1048576 + 67108864 + 1572864);  // 0.5 MB
  ushort_t* Qb      = (ushort_t*)(ws + 1048576 + 67108864 + 2097152);
  ushort_t* Kb      = Qb + 33554432ull;
  ushort_t* Vt      = Kb + 33554432ull;

  sort_chunk<<<32, 256, 0, stream>>>(codes, keys);
  for (int k = 4096; k <= 16384; k <<= 1) {
    for (int j = k >> 1; j >= 2048; j >>= 1)
      sort_gpass<<<256, 256, 0, stream>>>(keys, k, j);
    sort_finish<<<32, 256, 0, stream>>>(keys, k);
  }
  write_perm<<<256, 256, 0, stream>>>(keys, perm);

  gather_bf16<<<8192, 256, 0, stream>>>(feats, perm, Abf);
  convert_bf16<<<384, 256, 0, stream>>>(Wqkv, Wqkvbf);    // 786432 elems
  convert_bf16<<<128, 256, 0, stream>>>(Wproj, Wprojbf);  // 262144 elems

  qkv_gemm<<<6144, 256, 0, stream>>>(Abf, Wqkvbf, bqkv, Qb, Kb, Vt);
  attn_kernel<<<8192, 256, 0, stream>>>(Qb, Kb, Vt, perm, att);
  proj_gemm<<<2048, 256, 0, stream>>>(att, Wprojbf, bproj, out);
}

// Round 5
// 584.478 us; speedup vs baseline: 1.4804x; 1.4768x over previous
//
#include <hip/hip_runtime.h>
#include <hip/hip_bf16.h>

// PTV3 attention: sort -> gather+bf16 prepass -> bf16 QKV GEMM -> flash MHA
// (online softmax, swapped QK^T, scattered write) -> bf16 proj GEMM.
// GEMMs: m97 structure (global_load_lds w16, linear [128][64] LDS, XCD swizzle).

typedef unsigned long long u64;
typedef unsigned short ushort_t;
typedef __attribute__((ext_vector_type(8))) short short8v;
typedef __attribute__((ext_vector_type(4))) float f32x4;

#define MFMA_BF16 __builtin_amdgcn_mfma_f32_16x16x32_bf16

__device__ __forceinline__ unsigned short f2bf(float f) {
  union { float f; unsigned u; } v; v.f = f;
  return (unsigned short)((v.u + 0x7FFFu + ((v.u >> 16) & 1u)) >> 16);
}

__device__ __forceinline__ unsigned pk2(float a, float b) {
  __hip_bfloat162 h = __float22bfloat162_rn(float2{a, b});
  unsigned u; __builtin_memcpy(&u, &h, 4); return u;
}

// async global->LDS, 16B per lane; LDS dest = wave-uniform base + lane*16
__device__ __forceinline__ void async16(ushort_t* lds, const ushort_t* g) {
  __builtin_amdgcn_global_load_lds(
      (const __attribute__((address_space(1))) unsigned int*)g,
      (__attribute__((address_space(3))) unsigned int*)lds, 16, 0, 0);
}

// ---------------- stable sort of (code, idx) per 16384-group ----------------
// key = (code << 14) | idx  (code < 2^30, idx < 2^14) -> stable ascending sort.

__global__ __launch_bounds__(512) void sort_chunk(const int* __restrict__ codes,
                                                  u64* __restrict__ keys) {
  __shared__ u64 sk[4096];
  const int base = blockIdx.x * 4096;
  for (int t = threadIdx.x; t < 4096; t += 512) {
    int e = base + t;
    sk[t] = (((u64)(unsigned)codes[e]) << 14) | (u64)(e & 16383);
  }
  __syncthreads();
  for (int k = 2; k <= 4096; k <<= 1) {
    for (int j = k >> 1; j > 0; j >>= 1) {
      for (int t = threadIdx.x; t < 4096; t += 512) {
        int jx = t ^ j;
        if (jx > t) {
          bool up = (((base + t) & 16383 & k) == 0);
          u64 a = sk[t], b = sk[jx];
          if ((a > b) == up) { sk[t] = b; sk[jx] = a; }
        }
      }
      __syncthreads();
    }
  }
  for (int t = threadIdx.x; t < 4096; t += 512) keys[base + t] = sk[t];
}

__global__ __launch_bounds__(256) void sort_gpass(u64* __restrict__ keys, int k, int j) {
  int t = blockIdx.x * 256 + threadIdx.x;
  int jx = t ^ j;
  if (jx > t) {
    bool up = ((t & 16383 & k) == 0);
    u64 a = keys[t], b = keys[jx];
    if ((a > b) == up) { keys[t] = b; keys[jx] = a; }
  }
}

__global__ __launch_bounds__(512) void sort_finish(u64* __restrict__ keys, int k) {
  __shared__ u64 sk[4096];
  const int base = blockIdx.x * 4096;
  for (int t = threadIdx.x; t < 4096; t += 512) sk[t] = keys[base + t];
  __syncthreads();
  for (int j = 2048; j > 0; j >>= 1) {
    for (int t = threadIdx.x; t < 4096; t += 512) {
      int jx = t ^ j;
      if (jx > t) {
        bool up = (((base + t) & 16383 & k) == 0);
        u64 a = sk[t], b = sk[jx];
        if ((a > b) == up) { sk[t] = b; sk[jx] = a; }
      }
    }
    __syncthreads();
  }
  for (int t = threadIdx.x; t < 4096; t += 512) keys[base + t] = sk[t];
}

__global__ __launch_bounds__(256) void write_perm(const u64* __restrict__ keys,
                                                  int* __restrict__ perm) {
  int t = blockIdx.x * 256 + threadIdx.x;
  int g = t >> 14;
  int a = (int)(keys[t] & 16383);
  perm[t] = (g << 14) | a;        // perm[sorted pos] = original row
}

// ---------------- prepass: Abf[m][k] = bf16(feats[perm[m]][k]) ----------------

__global__ __launch_bounds__(256) void gather_bf16(const float* __restrict__ feats,
    const int* __restrict__ perm, ushort_t* __restrict__ A) {
  int t = blockIdx.x * 256 + threadIdx.x;
  int m = t >> 5;
  int off = (t & 31) << 4;
  const float* src = feats + (size_t)perm[m] * 512 + off;
  float4 a = ((const float4*)src)[0];
  float4 b = ((const float4*)src)[1];
  float4 c = ((const float4*)src)[2];
  float4 d = ((const float4*)src)[3];
  short8v lo = { (short)f2bf(a.x), (short)f2bf(a.y), (short)f2bf(a.z), (short)f2bf(a.w),
                 (short)f2bf(b.x), (short)f2bf(b.y), (short)f2bf(b.z), (short)f2bf(b.w) };
  short8v hi = { (short)f2bf(c.x), (short)f2bf(c.y), (short)f2bf(c.z), (short)f2bf(c.w),
                 (short)f2bf(d.x), (short)f2bf(d.y), (short)f2bf(d.z), (short)f2bf(d.w) };
  ushort_t* dst = A + (size_t)m * 512 + off;
  *(short8v*)(dst) = lo;
  *(short8v*)(dst + 8) = hi;
}

__global__ __launch_bounds__(256) void convert_bf16(const float* __restrict__ src,
                                                    ushort_t* __restrict__ dst) {
  int t = blockIdx.x * 256 + threadIdx.x;
  const float* s = src + (size_t)t * 8;
  float4 a = ((const float4*)s)[0];
  float4 b = ((const float4*)s)[1];
  short8v v = { (short)f2bf(a.x), (short)f2bf(a.y), (short)f2bf(a.z), (short)f2bf(a.w),
                (short)f2bf(b.x), (short)f2bf(b.y), (short)f2bf(b.z), (short)f2bf(b.w) };
  *(short8v*)(dst + (size_t)t * 8) = v;
}

// ---------------- QKV GEMM (bf16) ----------------

__global__ __launch_bounds__(256) void qkv_gemm(const ushort_t* __restrict__ A,
    const ushort_t* __restrict__ W, const float* __restrict__ bias,
    ushort_t* __restrict__ Q, ushort_t* __restrict__ Ko, ushort_t* __restrict__ Vt)
{
  __shared__ __align__(16) ushort_t la[128 * 64];
  __shared__ __align__(16) ushort_t lb[128 * 64];
  const int bid = blockIdx.x;                 // 6144 = 12 x 512, XCD-chunked
  const int swz = (bid & 7) * 768 + (bid >> 3);
  const int bx = swz % 12, by = swz / 12;
  const int rowBase = by * 128, colBase = bx * 128;
  const int tid = threadIdx.x, lane = tid & 63, w = tid >> 6;
  const int wr = w >> 1, wc = w & 1;
  const int li = lane & 15, kb = lane >> 4;
  const int lr = lane >> 3, lc = (lane & 7) << 3;
  f32x4 acc[4][4] = {};
  for (int kt = 0; kt < 8; ++kt) {
#pragma unroll
    for (int i = 0; i < 4; ++i) {
      int c = w * 4 + i;
      async16(la + c * 512, A + (size_t)(rowBase + c * 8 + lr) * 512 + kt * 64 + lc);
      async16(lb + c * 512, W + (size_t)(colBase + c * 8 + lr) * 512 + kt * 64 + lc);
    }
    __syncthreads();
    short8v af[2][4], bfr[2][4];
#pragma unroll
    for (int kk = 0; kk < 2; ++kk)
#pragma unroll
      for (int t = 0; t < 4; ++t) {
        af[kk][t]  = *(const short8v*)(la + (wr * 64 + t * 16 + li) * 64 + kk * 32 + kb * 8);
        bfr[kk][t] = *(const short8v*)(lb + (wc * 64 + t * 16 + li) * 64 + kk * 32 + kb * 8);
      }
#pragma unroll
    for (int kk = 0; kk < 2; ++kk)
#pragma unroll
      for (int i = 0; i < 4; ++i)
#pragma unroll
        for (int j = 0; j < 4; ++j)
          acc[i][j] = MFMA_BF16(af[kk][i], bfr[kk][j], acc[i][j], 0, 0, 0);
    __syncthreads();
  }
#pragma unroll
  for (int j = 0; j < 4; ++j) {
    int colb = colBase + wc * 64 + j * 16;
    int col = colb + li;
    float bv = bias[col];
    int c3 = colb >> 9;
    int h = (col >> 6) & 7;
    int d = col & 63;
#pragma unroll
    for (int i = 0; i < 4; ++i) {
      int m0 = rowBase + wr * 64 + i * 16 + kb * 4;
#pragma unroll
      for (int r = 0; r < 4; ++r) {
        int m = m0 + r;
        int n = m >> 9, p = m & 511;
        unsigned short bv16 = f2bf(acc[i][j][r] + bv);
        size_t nh = (size_t)(n * 8 + h);
        if (c3 == 0)      Q [(nh * 512 + p) * 64 + d] = bv16;
        else if (c3 == 1) Ko[(nh * 512 + p) * 64 + d] = bv16;
        else              Vt[(nh * 64 + d) * 512 + p] = bv16;
      }
    }
  }
}

// ---------------- flash attention: per (n,h,qc=64 rows), online softmax ----------------
// wave = 16 q-rows. Swapped QK^T: lane holds S[k=16t+4kb+r][q=li] -> k-reduce is
// lane-local + 2 shfl_xor. P transposed to A-frag layout via per-wave pbuf (no
// block barriers). Grid: b = (nh/8)*64 + qc*8 + (nh%8) -> same-nh blocks
// dispatch-adjacent AND same XCD (K/V fetched from HBM once).

__global__ __launch_bounds__(256) void attn_kernel(const ushort_t* __restrict__ Q,
    const ushort_t* __restrict__ K, const ushort_t* __restrict__ Vt,
    const int* __restrict__ perm, ushort_t* __restrict__ O)
{
  __shared__ __align__(16) ushort_t kbuf[64][72];
  __shared__ __align__(16) ushort_t vbuf[64][72];
  __shared__ __align__(16) ushort_t pbuf[4][16][72];
  const int b = blockIdx.x;
  const int qc = (b >> 3) & 7;
  const int nh = ((b >> 6) << 3) | (b & 7);
  const int n = nh >> 3, h = nh & 7;
  const int tid = threadIdx.x, w = tid >> 6, lane = tid & 63;
  const int li = lane & 15, kb = lane >> 4;
  const ushort_t* Qb = Q + (size_t)nh * (512 * 64);
  const ushort_t* Kb = K + (size_t)nh * (512 * 64);
  const ushort_t* Vb = Vt + (size_t)nh * (64 * 512);
  const int p0 = qc * 64 + w * 16;
  const int sgr = tid >> 3, sgc = (tid & 7) << 3;

  short8v qf0 = *(const short8v*)(Qb + (size_t)(p0 + li) * 64 + kb * 8);
  short8v qf1 = *(const short8v*)(Qb + (size_t)(p0 + li) * 64 + 32 + kb * 8);

  f32x4 o[4] = {};
  float m = -1e30f, l = 0.f;
  const float cs = 0.125f * 1.44269504088896340736f;  // scale * log2(e)

  for (int ch = 0; ch < 8; ++ch) {
#pragma unroll
    for (int st = 0; st < 2; ++st) {
      int r = st * 32 + sgr;
      *(short8v*)(&kbuf[r][sgc]) = *(const short8v*)(Kb + (size_t)(ch * 64 + r) * 64 + sgc);
      *(short8v*)(&vbuf[r][sgc]) = *(const short8v*)(Vb + (size_t)r * 512 + ch * 64 + sgc);
    }
    __syncthreads();
    // scores: S[k=16t+4kb+r][q=li]
    f32x4 s4[4];
#pragma unroll
    for (int t = 0; t < 4; ++t) {
      short8v kf0 = *(const short8v*)(&kbuf[t * 16 + li][kb * 8]);
      short8v kf1 = *(const short8v*)(&kbuf[t * 16 + li][32 + kb * 8]);
      f32x4 z = {0.f, 0.f, 0.f, 0.f};
      z = MFMA_BF16(kf0, qf0, z, 0, 0, 0);
      z = MFMA_BF16(kf1, qf1, z, 0, 0, 0);
      s4[t] = z;
    }
    // chunk row-max / exp / row-sum (per q=li)
    float pm = s4[0][0];
#pragma unroll
    for (int t = 0; t < 4; ++t)
#pragma unroll
      for (int r = 0; r < 4; ++r) pm = fmaxf(pm, s4[t][r]);
    pm = fmaxf(pm, __shfl_xor(pm, 16, 64));
    pm = fmaxf(pm, __shfl_xor(pm, 32, 64));
    float mn = fmaxf(m, pm);
    float rs = 0.f;
#pragma unroll
    for (int t = 0; t < 4; ++t)
#pragma unroll
      for (int r = 0; r < 4; ++r) {
        float e = exp2f((s4[t][r] - mn) * cs);
        s4[t][r] = e;
        rs += e;
      }
    rs += __shfl_xor(rs, 16, 64);
    rs += __shfl_xor(rs, 32, 64);
    float scale = exp2f((m - mn) * cs);
    l = l * scale + rs;
    m = mn;
    // P -> per-wave pbuf in A-frag layout (q-row = li, k contiguous)
#pragma unroll
    for (int t = 0; t < 4; ++t) {
      unsigned plo = pk2(s4[t][0], s4[t][1]);
      unsigned phi = pk2(s4[t][2], s4[t][3]);
      *(uint2*)(&pbuf[w][li][t * 16 + kb * 4]) = make_uint2(plo, phi);
    }
    // rescale O by per-q factor (fetch via width-16 shfl from lane li=kb*4+r)
    float sr4[4];
#pragma unroll
    for (int r = 0; r < 4; ++r) sr4[r] = __shfl(scale, ((lane >> 4) << 2) + r, 16);
#pragma unroll
    for (int dt = 0; dt < 4; ++dt)
#pragma unroll
      for (int r = 0; r < 4; ++r) o[dt][r] *= sr4[r];
    // PV
    short8v pa0 = *(const short8v*)(&pbuf[w][li][kb * 8]);
    short8v pa1 = *(const short8v*)(&pbuf[w][li][32 + kb * 8]);
#pragma unroll
    for (int dt = 0; dt < 4; ++dt) {
      short8v vf0 = *(const short8v*)(&vbuf[dt * 16 + li][kb * 8]);
      short8v vf1 = *(const short8v*)(&vbuf[dt * 16 + li][32 + kb * 8]);
      o[dt] = MFMA_BF16(pa0, vf0, o[dt], 0, 0, 0);
      o[dt] = MFMA_BF16(pa1, vf1, o[dt], 0, 0, 0);
    }
    __syncthreads();
  }
  float iv = 1.0f / l;
  float iv4[4];
#pragma unroll
  for (int r = 0; r < 4; ++r) iv4[r] = __shfl(iv, ((lane >> 4) << 2) + r, 16);
  int op[4];
#pragma unroll
  for (int r = 0; r < 4; ++r)
    op[r] = perm[n * 512 + p0 + kb * 4 + r];   // original row for sorted row
#pragma unroll
  for (int dt = 0; dt < 4; ++dt)
#pragma unroll
    for (int r = 0; r < 4; ++r)
      O[(size_t)op[r] * 512 + h * 64 + dt * 16 + li] = f2bf(o[dt][r] * iv4[r]);
}

// ---------------- proj GEMM (bf16) ----------------

__global__ __launch_bounds__(256) void proj_gemm(const ushort_t* __restrict__ A,
    const ushort_t* __restrict__ W, const float* __restrict__ bias,
    float* __restrict__ out)
{
  __shared__ __align__(16) ushort_t la[128 * 64];
  __shared__ __align__(16) ushort_t lb[128 * 64];
  const int bid = blockIdx.x;                 // 2048 = 4 x 512, XCD-chunked
  const int swz = (bid & 7) * 256 + (bid >> 3);
  const int bx = swz & 3, by = swz >> 2;
  const int rowBase = by * 128, colBase = bx * 128;
  const int tid = threadIdx.x, lane = tid & 63, w = tid >> 6;
  const int wr = w >> 1, wc = w & 1;
  const int li = lane & 15, kb = lane >> 4;
  const int lr = lane >> 3, lc = (lane & 7) << 3;
  f32x4 acc[4][4] = {};
  for (int kt = 0; kt < 8; ++kt) {
#pragma unroll
    for (int i = 0; i < 4; ++i) {
      int c = w * 4 + i;
      async16(la + c * 512, A + (size_t)(rowBase + c * 8 + lr) * 512 + kt * 64 + lc);
      async16(lb + c * 512, W + (size_t)(colBase + c * 8 + lr) * 512 + kt * 64 + lc);
    }
    __syncthreads();
    short8v af[2][4], bfr[2][4];
#pragma unroll
    for (int kk = 0; kk < 2; ++kk)
#pragma unroll
      for (int t = 0; t < 4; ++t) {
        af[kk][t]  = *(const short8v*)(la + (wr * 64 + t * 16 + li) * 64 + kk * 32 + kb * 8);
        bfr[kk][t] = *(const short8v*)(lb + (wc * 64 + t * 16 + li) * 64 + kk * 32 + kb * 8);
      }
#pragma unroll
    for (int kk = 0; kk < 2; ++kk)
#pragma unroll
      for (int i = 0; i < 4; ++i)
#pragma unroll
        for (int j = 0; j < 4; ++j)
          acc[i][j] = MFMA_BF16(af[kk][i], bfr[kk][j], acc[i][j], 0, 0, 0);
    __syncthreads();
  }
#pragma unroll
  for (int i = 0; i < 4; ++i)
#pragma unroll
    for (int j = 0; j < 4; ++j) {
      int col = colBase + wc * 64 + j * 16 + li;
      float bv = bias[col];
#pragma unroll
      for (int r = 0; r < 4; ++r) {
        int m = rowBase + wr * 64 + i * 16 + kb * 4 + r;
        out[(size_t)m * 512 + col] = acc[i][j][r] + bv;
      }
    }
}

// ---------------- launch ----------------

extern "C" void kernel_launch(void* const* d_in, const int* in_sizes, int n_in,
                              void* d_out, int out_size, void* d_ws, size_t ws_size,
                              hipStream_t stream) {
  (void)in_sizes; (void)n_in; (void)out_size; (void)ws_size;
  const float* feats      = (const float*)d_in[0];
  const int* codes        = (const int*)d_in[1];   // int64 in reference, delivered as int32
  const float* Wqkv       = (const float*)d_in[2];
  const float* bqkv       = (const float*)d_in[3];
  const float* Wproj      = (const float*)d_in[4];
  const float* bproj      = (const float*)d_in[5];
  float* out = (float*)d_out;

  char* ws = (char*)d_ws;
  int* perm = (int*)(ws);
  u64* keys = (u64*)(ws + 262144);
  ushort_t* Abf     = (ushort_t*)(ws + 1048576);                       // 64 MB
  ushort_t* att     = Abf;                                             // reuse
  ushort_t* Wqkvbf  = (ushort_t*)(ws + 1048576 + 67108864);            // 1.5 MB
  ushort_t* Wprojbf = (ushort_t*)(ws + 1048576 + 67108864 + 1572864);  // 0.5 MB
  ushort_t* Qb      = (ushort_t*)(ws + 1048576 + 67108864 + 2097152);
  ushort_t* Kb      = Qb + 33554432ull;
  ushort_t* Vt      = Kb + 33554432ull;

  sort_chunk<<<16, 512, 0, stream>>>(codes, keys);
  sort_gpass<<<256, 256, 0, stream>>>(keys, 8192, 4096);
  sort_finish<<<16, 512, 0, stream>>>(keys, 8192);
  sort_gpass<<<256, 256, 0, stream>>>(keys, 16384, 8192);
  sort_gpass<<<256, 256, 0, stream>>>(keys, 16384, 4096);
  sort_finish<<<16, 512, 0, stream>>>(keys, 16384);
  write_perm<<<256, 256, 0, stream>>>(keys, perm);

  gather_bf16<<<8192, 256, 0, stream>>>(feats, perm, Abf);
  convert_bf16<<<384, 256, 0, stream>>>(Wqkv, Wqkvbf);
  convert_bf16<<<128, 256, 0, stream>>>(Wproj, Wprojbf);

  qkv_gemm<<<6144, 256, 0, stream>>>(Abf, Wqkvbf, bqkv, Qb, Kb, Vt);
  attn_kernel<<<8192, 256, 0, stream>>>(Qb, Kb, Vt, perm, att);
  proj_gemm<<<2048, 256, 0, stream>>>(att, Wprojbf, bproj, out);
}

// Round 7
// 502.436 us; speedup vs baseline: 1.7221x; 1.1633x over previous
//
#include <hip/hip_runtime.h>
#include <hip/hip_bf16.h>

// PTV3 attention: sort -> gather+bf16 prepass -> bf16 QKV GEMM -> flash MHA
// (online softmax, swapped QK^T, scattered write) -> bf16 proj GEMM.
// GEMMs: m97 structure + T2 XOR swizzle (linear LDS dest, pre-swizzled global
// source, swizzled ds_read — rule #21) + coalesced Vt epilogue via LDS transpose.

typedef unsigned long long u64;
typedef unsigned short ushort_t;
typedef __attribute__((ext_vector_type(8))) short short8v;
typedef __attribute__((ext_vector_type(4))) float f32x4;

#define MFMA_BF16 __builtin_amdgcn_mfma_f32_16x16x32_bf16

__device__ __forceinline__ unsigned short f2bf(float f) {
  union { float f; unsigned u; } v; v.f = f;
  return (unsigned short)((v.u + 0x7FFFu + ((v.u >> 16) & 1u)) >> 16);
}

__device__ __forceinline__ unsigned pk2(float a, float b) {
  __hip_bfloat162 h = __float22bfloat162_rn(float2{a, b});
  unsigned u; __builtin_memcpy(&u, &h, 4); return u;
}

// async global->LDS, 16B per lane; LDS dest = wave-uniform base + lane*16
__device__ __forceinline__ void async16(ushort_t* lds, const ushort_t* g) {
  __builtin_amdgcn_global_load_lds(
      (const __attribute__((address_space(1))) unsigned int*)g,
      (__attribute__((address_space(3))) unsigned int*)lds, 16, 0, 0);
}

// ---------------- stable sort of (code, idx) per 16384-group ----------------

__global__ __launch_bounds__(512) void sort_chunk(const int* __restrict__ codes,
                                                  u64* __restrict__ keys) {
  __shared__ u64 sk[4096];
  const int base = blockIdx.x * 4096;
  for (int t = threadIdx.x; t < 4096; t += 512) {
    int e = base + t;
    sk[t] = (((u64)(unsigned)codes[e]) << 14) | (u64)(e & 16383);
  }
  __syncthreads();
  for (int k = 2; k <= 4096; k <<= 1) {
    for (int j = k >> 1; j > 0; j >>= 1) {
      for (int t = threadIdx.x; t < 4096; t += 512) {
        int jx = t ^ j;
        if (jx > t) {
          bool up = (((base + t) & 16383 & k) == 0);
          u64 a = sk[t], b = sk[jx];
          if ((a > b) == up) { sk[t] = b; sk[jx] = a; }
        }
      }
      __syncthreads();
    }
  }
  for (int t = threadIdx.x; t < 4096; t += 512) keys[base + t] = sk[t];
}

__global__ __launch_bounds__(256) void sort_gpass(u64* __restrict__ keys, int k, int j) {
  int t = blockIdx.x * 256 + threadIdx.x;
  int jx = t ^ j;
  if (jx > t) {
    bool up = ((t & 16383 & k) == 0);
    u64 a = keys[t], b = keys[jx];
    if ((a > b) == up) { keys[t] = b; keys[jx] = a; }
  }
}

__global__ __launch_bounds__(512) void sort_finish(u64* __restrict__ keys, int k) {
  __shared__ u64 sk[4096];
  const int base = blockIdx.x * 4096;
  for (int t = threadIdx.x; t < 4096; t += 512) sk[t] = keys[base + t];
  __syncthreads();
  for (int j = 2048; j > 0; j >>= 1) {
    for (int t = threadIdx.x; t < 4096; t += 512) {
      int jx = t ^ j;
      if (jx > t) {
        bool up = (((base + t) & 16383 & k) == 0);
        u64 a = sk[t], b = sk[jx];
        if ((a > b) == up) { sk[t] = b; sk[jx] = a; }
      }
    }
    __syncthreads();
  }
  for (int t = threadIdx.x; t < 4096; t += 512) keys[base + t] = sk[t];
}

__global__ __launch_bounds__(256) void write_perm(const u64* __restrict__ keys,
                                                  int* __restrict__ perm) {
  int t = blockIdx.x * 256 + threadIdx.x;
  int g = t >> 14;
  int a = (int)(keys[t] & 16383);
  perm[t] = (g << 14) | a;        // perm[sorted pos] = original row
}

// ---------------- prepass: Abf[m][k] = bf16(feats[perm[m]][k]) ----------------

__global__ __launch_bounds__(256) void gather_bf16(const float* __restrict__ feats,
    const int* __restrict__ perm, ushort_t* __restrict__ A) {
  int t = blockIdx.x * 256 + threadIdx.x;
  int m = t >> 5;
  int off = (t & 31) << 4;
  const float* src = feats + (size_t)perm[m] * 512 + off;
  float4 a = ((const float4*)src)[0];
  float4 b = ((const float4*)src)[1];
  float4 c = ((const float4*)src)[2];
  float4 d = ((const float4*)src)[3];
  short8v lo = { (short)f2bf(a.x), (short)f2bf(a.y), (short)f2bf(a.z), (short)f2bf(a.w),
                 (short)f2bf(b.x), (short)f2bf(b.y), (short)f2bf(b.z), (short)f2bf(b.w) };
  short8v hi = { (short)f2bf(c.x), (short)f2bf(c.y), (short)f2bf(c.z), (short)f2bf(c.w),
                 (short)f2bf(d.x), (short)f2bf(d.y), (short)f2bf(d.z), (short)f2bf(d.w) };
  ushort_t* dst = A + (size_t)m * 512 + off;
  *(short8v*)(dst) = lo;
  *(short8v*)(dst + 8) = hi;
}

__global__ __launch_bounds__(256) void convert_bf16(const float* __restrict__ src,
                                                    ushort_t* __restrict__ dst) {
  int t = blockIdx.x * 256 + threadIdx.x;
  const float* s = src + (size_t)t * 8;
  float4 a = ((const float4*)s)[0];
  float4 b = ((const float4*)s)[1];
  short8v v = { (short)f2bf(a.x), (short)f2bf(a.y), (short)f2bf(a.z), (short)f2bf(a.w),
                (short)f2bf(b.x), (short)f2bf(b.y), (short)f2bf(b.z), (short)f2bf(b.w) };
  *(short8v*)(dst + (size_t)t * 8) = v;
}

// ---------------- QKV GEMM (bf16), T2-swizzled LDS ----------------
// LDS content: lds(row, slot16) = g(row, slot16 ^ (row&7)); involution on both sides.

__global__ __launch_bounds__(256) void qkv_gemm(const ushort_t* __restrict__ A,
    const ushort_t* __restrict__ W, const float* __restrict__ bias,
    ushort_t* __restrict__ Q, ushort_t* __restrict__ Ko, ushort_t* __restrict__ Vt)
{
  __shared__ __align__(16) ushort_t la[128 * 64];
  __shared__ __align__(16) ushort_t lb[128 * 64];
  const int bid = blockIdx.x;                 // 6144 = 12 x 512, XCD-chunked
  const int swz = (bid & 7) * 768 + (bid >> 3);
  const int bx = swz % 12, by = swz / 12;
  const int rowBase = by * 128, colBase = bx * 128;
  const int tid = threadIdx.x, lane = tid & 63, w = tid >> 6;
  const int wr = w >> 1, wc = w & 1;
  const int li = lane & 15, kb = lane >> 4;
  const int lr = lane >> 3;
  const int lcs = (((lane & 7) ^ lr) << 3);   // pre-swizzled source col (elems)
  f32x4 acc[4][4] = {};
  for (int kt = 0; kt < 8; ++kt) {
#pragma unroll
    for (int i = 0; i < 4; ++i) {
      int c = w * 4 + i;
      async16(la + c * 512, A + (size_t)(rowBase + c * 8 + lr) * 512 + kt * 64 + lcs);
      async16(lb + c * 512, W + (size_t)(colBase + c * 8 + lr) * 512 + kt * 64 + lcs);
    }
    __syncthreads();
    short8v af[2][4], bfr[2][4];
#pragma unroll
    for (int kk = 0; kk < 2; ++kk)
#pragma unroll
      for (int t = 0; t < 4; ++t) {
        int sl = ((kk * 4 + kb) ^ (li & 7)) << 3;   // swizzled read slot
        af[kk][t]  = *(const short8v*)(la + (wr * 64 + t * 16 + li) * 64 + sl);
        bfr[kk][t] = *(const short8v*)(lb + (wc * 64 + t * 16 + li) * 64 + sl);
      }
#pragma unroll
    for (int kk = 0; kk < 2; ++kk)
#pragma unroll
      for (int i = 0; i < 4; ++i)
#pragma unroll
        for (int j = 0; j < 4; ++j)
          acc[i][j] = MFMA_BF16(af[kk][i], bfr[kk][j], acc[i][j], 0, 0, 0);
    __syncthreads();
  }
  const int c0 = colBase + wc * 64;           // wave's first global col
  if (c0 >= 1024) {
    // ---- V block: transpose 64x64 subtile via private LDS, store p-contiguous ----
    ushort_t* tw = (w < 2) ? (la + w * 4096) : (lb + (w - 2) * 4096);
    char* twb = (char*)tw;
#pragma unroll
    for (int j = 0; j < 4; ++j) {
      int dloc = j * 16 + li;
      float bv = bias[c0 + dloc];
#pragma unroll
      for (int i = 0; i < 4; ++i) {
        unsigned u0 = pk2(acc[i][j][0] + bv, acc[i][j][1] + bv);
        unsigned u1 = pk2(acc[i][j][2] + bv, acc[i][j][3] + bv);
        int s = i * 2 + (kb >> 1);
        int byte = dloc * 128 + ((s ^ (dloc & 7)) << 4) + ((kb & 1) << 3);
        *(uint2*)(twb + byte) = make_uint2(u0, u1);
      }
    }
    const int h = (c0 - 1024) >> 6;
    const size_t nh = (size_t)((rowBase >> 9) * 8 + h);
    const int pbase = ((rowBase + wr * 64) & 511) + ((lane & 7) << 3);
    ushort_t* vb = Vt + nh * 32768 + pbase;
#pragma unroll
    for (int ps = 0; ps < 8; ++ps) {
      int dloc = ps * 8 + (lane >> 3);
      int byte = dloc * 128 + ((((lane & 7)) ^ (dloc & 7)) << 4);
      short8v vv = *(const short8v*)(twb + byte);
      *(short8v*)(vb + dloc * 512) = vv;
    }
  } else {
    // ---- Q/K block: original store path ----
#pragma unroll
    for (int j = 0; j < 4; ++j) {
      int colb = c0 + j * 16;
      int col = colb + li;
      float bv = bias[col];
      int c3 = colb >> 9;
      int h = (col >> 6) & 7;
      int d = col & 63;
#pragma unroll
      for (int i = 0; i < 4; ++i) {
        int m0 = rowBase + wr * 64 + i * 16 + kb * 4;
#pragma unroll
        for (int r = 0; r < 4; ++r) {
          int m = m0 + r;
          int n = m >> 9, p = m & 511;
          unsigned short bv16 = f2bf(acc[i][j][r] + bv);
          size_t nh = (size_t)(n * 8 + h);
          if (c3 == 0) Q [(nh * 512 + p) * 64 + d] = bv16;
          else         Ko[(nh * 512 + p) * 64 + d] = bv16;
        }
      }
    }
  }
}

// ---------------- flash attention (unchanged) ----------------

__global__ __launch_bounds__(256) void attn_kernel(const ushort_t* __restrict__ Q,
    const ushort_t* __restrict__ K, const ushort_t* __restrict__ Vt,
    const int* __restrict__ perm, ushort_t* __restrict__ O)
{
  __shared__ __align__(16) ushort_t kbuf[64][72];
  __shared__ __align__(16) ushort_t vbuf[64][72];
  __shared__ __align__(16) ushort_t pbuf[4][16][72];
  const int b = blockIdx.x;
  const int qc = (b >> 3) & 7;
  const int nh = ((b >> 6) << 3) | (b & 7);
  const int n = nh >> 3, h = nh & 7;
  const int tid = threadIdx.x, w = tid >> 6, lane = tid & 63;
  const int li = lane & 15, kb = lane >> 4;
  const ushort_t* Qb = Q + (size_t)nh * (512 * 64);
  const ushort_t* Kb = K + (size_t)nh * (512 * 64);
  const ushort_t* Vb = Vt + (size_t)nh * (64 * 512);
  const int p0 = qc * 64 + w * 16;
  const int sgr = tid >> 3, sgc = (tid & 7) << 3;

  short8v qf0 = *(const short8v*)(Qb + (size_t)(p0 + li) * 64 + kb * 8);
  short8v qf1 = *(const short8v*)(Qb + (size_t)(p0 + li) * 64 + 32 + kb * 8);

  f32x4 o[4] = {};
  float m = -1e30f, l = 0.f;
  const float cs = 0.125f * 1.44269504088896340736f;  // scale * log2(e)

  for (int ch = 0; ch < 8; ++ch) {
#pragma unroll
    for (int st = 0; st < 2; ++st) {
      int r = st * 32 + sgr;
      *(short8v*)(&kbuf[r][sgc]) = *(const short8v*)(Kb + (size_t)(ch * 64 + r) * 64 + sgc);
      *(short8v*)(&vbuf[r][sgc]) = *(const short8v*)(Vb + (size_t)r * 512 + ch * 64 + sgc);
    }
    __syncthreads();
    f32x4 s4[4];
#pragma unroll
    for (int t = 0; t < 4; ++t) {
      short8v kf0 = *(const short8v*)(&kbuf[t * 16 + li][kb * 8]);
      short8v kf1 = *(const short8v*)(&kbuf[t * 16 + li][32 + kb * 8]);
      f32x4 z = {0.f, 0.f, 0.f, 0.f};
      z = MFMA_BF16(kf0, qf0, z, 0, 0, 0);
      z = MFMA_BF16(kf1, qf1, z, 0, 0, 0);
      s4[t] = z;
    }
    float pm = s4[0][0];
#pragma unroll
    for (int t = 0; t < 4; ++t)
#pragma unroll
      for (int r = 0; r < 4; ++r) pm = fmaxf(pm, s4[t][r]);
    pm = fmaxf(pm, __shfl_xor(pm, 16, 64));
    pm = fmaxf(pm, __shfl_xor(pm, 32, 64));
    float mn = fmaxf(m, pm);
    float rs = 0.f;
#pragma unroll
    for (int t = 0; t < 4; ++t)
#pragma unroll
      for (int r = 0; r < 4; ++r) {
        float e = exp2f((s4[t][r] - mn) * cs);
        s4[t][r] = e;
        rs += e;
      }
    rs += __shfl_xor(rs, 16, 64);
    rs += __shfl_xor(rs, 32, 64);
    float scale = exp2f((m - mn) * cs);
    l = l * scale + rs;
    m = mn;
#pragma unroll
    for (int t = 0; t < 4; ++t) {
      unsigned plo = pk2(s4[t][0], s4[t][1]);
      unsigned phi = pk2(s4[t][2], s4[t][3]);
      *(uint2*)(&pbuf[w][li][t * 16 + kb * 4]) = make_uint2(plo, phi);
    }
    float sr4[4];
#pragma unroll
    for (int r = 0; r < 4; ++r) sr4[r] = __shfl(scale, ((lane >> 4) << 2) + r, 16);
#pragma unroll
    for (int dt = 0; dt < 4; ++dt)
#pragma unroll
      for (int r = 0; r < 4; ++r) o[dt][r] *= sr4[r];
    short8v pa0 = *(const short8v*)(&pbuf[w][li][kb * 8]);
    short8v pa1 = *(const short8v*)(&pbuf[w][li][32 + kb * 8]);
#pragma unroll
    for (int dt = 0; dt < 4; ++dt) {
      short8v vf0 = *(const short8v*)(&vbuf[dt * 16 + li][kb * 8]);
      short8v vf1 = *(const short8v*)(&vbuf[dt * 16 + li][32 + kb * 8]);
      o[dt] = MFMA_BF16(pa0, vf0, o[dt], 0, 0, 0);
      o[dt] = MFMA_BF16(pa1, vf1, o[dt], 0, 0, 0);
    }
    __syncthreads();
  }
  float iv = 1.0f / l;
  float iv4[4];
#pragma unroll
  for (int r = 0; r < 4; ++r) iv4[r] = __shfl(iv, ((lane >> 4) << 2) + r, 16);
  int op[4];
#pragma unroll
  for (int r = 0; r < 4; ++r)
    op[r] = perm[n * 512 + p0 + kb * 4 + r];
#pragma unroll
  for (int dt = 0; dt < 4; ++dt)
#pragma unroll
    for (int r = 0; r < 4; ++r)
      O[(size_t)op[r] * 512 + h * 64 + dt * 16 + li] = f2bf(o[dt][r] * iv4[r]);
}

// ---------------- proj GEMM (bf16), T2-swizzled LDS ----------------

__global__ __launch_bounds__(256) void proj_gemm(const ushort_t* __restrict__ A,
    const ushort_t* __restrict__ W, const float* __restrict__ bias,
    float* __restrict__ out)
{
  __shared__ __align__(16) ushort_t la[128 * 64];
  __shared__ __align__(16) ushort_t lb[128 * 64];
  const int bid = blockIdx.x;                 // 2048 = 4 x 512, XCD-chunked
  const int swz = (bid & 7) * 256 + (bid >> 3);
  const int bx = swz & 3, by = swz >> 2;
  const int rowBase = by * 128, colBase = bx * 128;
  const int tid = threadIdx.x, lane = tid & 63, w = tid >> 6;
  const int wr = w >> 1, wc = w & 1;
  const int li = lane & 15, kb = lane >> 4;
  const int lr = lane >> 3;
  const int lcs = (((lane & 7) ^ lr) << 3);
  f32x4 acc[4][4] = {};
  for (int kt = 0; kt < 8; ++kt) {
#pragma unroll
    for (int i = 0; i < 4; ++i) {
      int c = w * 4 + i;
      async16(la + c * 512, A + (size_t)(rowBase + c * 8 + lr) * 512 + kt * 64 + lcs);
      async16(lb + c * 512, W + (size_t)(colBase + c * 8 + lr) * 512 + kt * 64 + lcs);
    }
    __syncthreads();
    short8v af[2][4], bfr[2][4];
#pragma unroll
    for (int kk = 0; kk < 2; ++kk)
#pragma unroll
      for (int t = 0; t < 4; ++t) {
        int sl = ((kk * 4 + kb) ^ (li & 7)) << 3;
        af[kk][t]  = *(const short8v*)(la + (wr * 64 + t * 16 + li) * 64 + sl);
        bfr[kk][t] = *(const short8v*)(lb + (wc * 64 + t * 16 + li) * 64 + sl);
      }
#pragma unroll
    for (int kk = 0; kk < 2; ++kk)
#pragma unroll
      for (int i = 0; i < 4; ++i)
#pragma unroll
        for (int j = 0; j < 4; ++j)
          acc[i][j] = MFMA_BF16(af[kk][i], bfr[kk][j], acc[i][j], 0, 0, 0);
    __syncthreads();
  }
#pragma unroll
  for (int i = 0; i < 4; ++i)
#pragma unroll
    for (int j = 0; j < 4; ++j) {
      int col = colBase + wc * 64 + j * 16 + li;
      float bv = bias[col];
#pragma unroll
      for (int r = 0; r < 4; ++r) {
        int m = rowBase + wr * 64 + i * 16 + kb * 4 + r;
        out[(size_t)m * 512 + col] = acc[i][j][r] + bv;
      }
    }
}

// ---------------- launch ----------------

extern "C" void kernel_launch(void* const* d_in, const int* in_sizes, int n_in,
                              void* d_out, int out_size, void* d_ws, size_t ws_size,
                              hipStream_t stream) {
  (void)in_sizes; (void)n_in; (void)out_size; (void)ws_size;
  const float* feats      = (const float*)d_in[0];
  const int* codes        = (const int*)d_in[1];   // int64 in reference, delivered as int32
  const float* Wqkv       = (const float*)d_in[2];
  const float* bqkv       = (const float*)d_in[3];
  const float* Wproj      = (const float*)d_in[4];
  const float* bproj      = (const float*)d_in[5];
  float* out = (float*)d_out;

  char* ws = (char*)d_ws;
  int* perm = (int*)(ws);
  u64* keys = (u64*)(ws + 262144);
  ushort_t* Abf     = (ushort_t*)(ws + 1048576);                       // 64 MB
  ushort_t* att     = Abf;                                             // reuse
  ushort_t* Wqkvbf  = (ushort_t*)(ws + 1048576 + 67108864);            // 1.5 MB
  ushort_t* Wprojbf = (ushort_t*)(ws + 1048576 + 67108864 + 1572864);  // 0.5 MB
  ushort_t* Qb      = (ushort_t*)(ws + 1048576 + 67108864 + 2097152);
  ushort_t* Kb      = Qb + 33554432ull;
  ushort_t* Vt      = Kb + 33554432ull;

  sort_chunk<<<16, 512, 0, stream>>>(codes, keys);
  sort_gpass<<<256, 256, 0, stream>>>(keys, 8192, 4096);
  sort_finish<<<16, 512, 0, stream>>>(keys, 8192);
  sort_gpass<<<256, 256, 0, stream>>>(keys, 16384, 8192);
  sort_gpass<<<256, 256, 0, stream>>>(keys, 16384, 4096);
  sort_finish<<<16, 512, 0, stream>>>(keys, 16384);
  write_perm<<<256, 256, 0, stream>>>(keys, perm);

  gather_bf16<<<8192, 256, 0, stream>>>(feats, perm, Abf);
  convert_bf16<<<384, 256, 0, stream>>>(Wqkv, Wqkvbf);
  convert_bf16<<<128, 256, 0, stream>>>(Wproj, Wprojbf);

  qkv_gemm<<<6144, 256, 0, stream>>>(Abf, Wqkvbf, bqkv, Qb, Kb, Vt);
  attn_kernel<<<8192, 256, 0, stream>>>(Qb, Kb, Vt, perm, att);
  proj_gemm<<<2048, 256, 0, stream>>>(att, Wprojbf, bproj, out);
}